// Round 14
// baseline (155.798 us; speedup 1.0000x reference)
//
#include <hip/hip_runtime.h>

#define NNODES 40000
#define NEDGES 640000
#define NFEAT  256
#define NHID   128

// ---- window partition geometry ----
#define WSH    5                        // 32 nodes per window
#define WNODES 32
#define NW     1250                     // 40000/32 exactly
#define PARTB  250                      // fill blocks
#define EPT    10
#define EPB    2560                     // edges per fill block
#define CSLOTS 16                       // cell = 1 header u64 + 15 record slots
#define CAPREC 15                       // records per cell; lambda=2.05, P(>15)~6e-10
#define CAPW   1024                     // gather srec cap; E[cnt]=512
#define GEMM_BLOCKS (NNODES / 64)       // 625

// ---- workspace layout (bytes; ws_size = 256 MiB per R9 poison evidence) ----
#define SUP_OFF  0u                     // support bf16: 10,240,000
#define WT_OFF   10240000u              // Wt bf16: 65,536
#define EBIN_OFF 10305536u              // ebin u64 [NW][PARTB][CSLOTS]: 40,000,000
#define WS_NEEDED (EBIN_OFF + (size_t)NW * PARTB * CSLOTS * 8)   // 50,305,536

typedef float floatx4 __attribute__((ext_vector_type(4)));
typedef __bf16 bf16x8 __attribute__((ext_vector_type(8)));
typedef unsigned short ushort8 __attribute__((ext_vector_type(8)));
union BfFrag { ushort8 s; bf16x8 b; };

__device__ __forceinline__ unsigned short f2bf(float f) {
    unsigned int u = __float_as_uint(f);
    u = (u + 0x7FFFu + ((u >> 16) & 1u)) >> 16;   // RNE
    return (unsigned short)u;
}

// decode 2x(2 bf16) -> float4
__device__ __forceinline__ float4 bf4(unsigned int lo, unsigned int hi) {
    float4 v;
    v.x = __uint_as_float(lo << 16);
    v.y = __uint_as_float(lo & 0xFFFF0000u);
    v.z = __uint_as_float(hi << 16);
    v.w = __uint_as_float(hi & 0xFFFF0000u);
    return v;
}

// ---------------------------------------------------------------------------
// K0: setup — Wt[h][k] = bf16(W[k][h]) only.
// ---------------------------------------------------------------------------
__global__ __launch_bounds__(256) void setup_wt(const float* __restrict__ W,
                                                unsigned short* __restrict__ Wt) {
    const int i = blockIdx.x * 256 + threadIdx.x;
    const int h = i >> 8;
    const int k = i & 255;
    Wt[i] = f2bf(W[k * NHID + h]);
}

// ---------------------------------------------------------------------------
// K1: GEMM (blocks [0,625)) || fill (blocks [625,875)).
// Fill: block pb OWNS cell [rw][pb] (header + 15 slots) for every window rw.
// R13 lesson: a separate cnt array cost ~20MB of line-granular reads
// (2B count per 64B line). The count now lives in the cell's slot 0 —
// written into the block's own already-dirty private line, read by gather
// in the same line as the first 6 records.
// ---------------------------------------------------------------------------
__global__ __launch_bounds__(256) void gemm_fill(const float* __restrict__ x,
                                                 const unsigned short* __restrict__ Wt,
                                                 unsigned short* __restrict__ support,
                                                 const int* __restrict__ ei,
                                                 const float* __restrict__ ew,
                                                 unsigned long long* __restrict__ ebin) {
    const int tid = threadIdx.x;

    if (blockIdx.x >= GEMM_BLOCKS) {
        // ---- fill path ----
        __shared__ unsigned int ldscur[NW];          // 5000 B
        const int pb   = blockIdx.x - GEMM_BLOCKS;
        const int base = pb * EPB + tid;

        for (int i = tid; i < NW; i += 256) ldscur[i] = 0u;
        __syncthreads();

        int src[EPT], dst[EPT];
        float w[EPT];
        #pragma unroll
        for (int j = 0; j < EPT; j++) {
            const int e = base + j * 256;
            src[j] = ei[e];
            dst[j] = ei[NEDGES + e];
            w[j]   = ew[e];
        }
        #pragma unroll
        for (int j = 0; j < EPT; j++) {
            const int rw = dst[j] >> WSH;
            const unsigned int idx = atomicAdd(&ldscur[rw], 1u);
            if (idx < CAPREC) {
                const unsigned long long rec =
                    ((unsigned long long)f2bf(w[j]) << 32)
                  | ((unsigned long long)(dst[j] & (WNODES - 1)) << 16)
                  | (unsigned long long)(unsigned int)src[j];
                ebin[((size_t)rw * PARTB + pb) * CSLOTS + 1 + idx] = rec;
            }
        }
        __syncthreads();

        for (int i = tid; i < NW; i += 256) {        // strided (R10 lesson)
            unsigned int c = ldscur[i];
            if (c > CAPREC) c = CAPREC;
            ebin[((size_t)i * PARTB + pb) * CSLOTS] = (unsigned long long)c;
        }
        return;
    }

    // ---- GEMM path (unchanged, proven) ----
    const int lane = tid & 63;
    const int wv   = tid >> 6;
    const int m    = lane & 15;
    const int quad = lane >> 4;
    const int node = blockIdx.x * 64 + wv * 16 + m;

    BfFrag afrag[8];
    const float* xrow = x + (size_t)node * NFEAT + quad * 8;
    #pragma unroll
    for (int ks = 0; ks < 8; ks++) {
        float4 f0 = *(const float4*)(xrow + ks * 32);
        float4 f1 = *(const float4*)(xrow + ks * 32 + 4);
        afrag[ks].s[0] = f2bf(f0.x); afrag[ks].s[1] = f2bf(f0.y);
        afrag[ks].s[2] = f2bf(f0.z); afrag[ks].s[3] = f2bf(f0.w);
        afrag[ks].s[4] = f2bf(f1.x); afrag[ks].s[5] = f2bf(f1.y);
        afrag[ks].s[6] = f2bf(f1.z); afrag[ks].s[7] = f2bf(f1.w);
    }

    floatx4 acc[8];
    #pragma unroll
    for (int nt = 0; nt < 8; nt++) acc[nt] = (floatx4){0.f, 0.f, 0.f, 0.f};

    #pragma unroll
    for (int nt = 0; nt < 8; nt++) {
        const unsigned short* wrow = Wt + (size_t)(nt * 16 + m) * NFEAT + quad * 8;
        #pragma unroll
        for (int ks = 0; ks < 8; ks++) {
            BfFrag bfrag;
            bfrag.s = *(const ushort8*)(wrow + ks * 32);
            acc[nt] = __builtin_amdgcn_mfma_f32_16x16x32_bf16(afrag[ks].b, bfrag.b,
                                                              acc[nt], 0, 0, 0);
        }
    }

    const int row0 = blockIdx.x * 64 + wv * 16 + quad * 4;
    #pragma unroll
    for (int nt = 0; nt < 8; nt++) {
        #pragma unroll
        for (int r = 0; r < 4; r++) {
            support[(size_t)(row0 + r) * NHID + nt * 16 + m] = f2bf(acc[nt][r]);
        }
    }
}

// ---------------------------------------------------------------------------
// K2: gather — one block (512 thr) per 32-node window, 1250 blocks.
// Thread t<250 reads cell [rw][t]: header + ~2 records, one line typical.
// Histogram 32 bins -> 5-pass scan -> scatter into srec (8KB) -> walk with
// 16 lanes/node, 8 hids/lane, DUAL-STREAM (2 records in flight per lane,
// independent accumulator pairs merged at epilogue). Zero fp atomics.
// ---------------------------------------------------------------------------
__global__ __launch_bounds__(512) void gather_range(
        const unsigned long long* __restrict__ ebin,
        const unsigned short* __restrict__ support,
        const float* __restrict__ b,
        float* __restrict__ out) {
    __shared__ unsigned long long srec[CAPW];        // 8192 B
    __shared__ unsigned int hcnt[WNODES];
    __shared__ unsigned int hstart[WNODES + 1];
    __shared__ unsigned int sA[WNODES], sB[WNODES];

    const int rw  = blockIdx.x;                      // window: nodes [rw*32, rw*32+32)
    const int tid = threadIdx.x;

    const unsigned long long* seg =
        ebin + ((size_t)rw * PARTB + (tid < PARTB ? tid : 0)) * CSLOTS;
    unsigned int c_t = 0;
    if (tid < PARTB) {
        c_t = (unsigned int)seg[0];                  // header: count
        if (c_t > CAPREC) c_t = CAPREC;
    }
    if (tid < WNODES) hcnt[tid] = 0u;
    __syncthreads();

    // pass 1: histogram dl (records at slots 1..c_t, same line as header)
    for (unsigned int k = 0; k < c_t; ++k)
        atomicAdd(&hcnt[(unsigned int)(seg[1 + k] >> 16) & (WNODES - 1)], 1u);
    __syncthreads();

    // exclusive scan over 32 (Hillis-Steele, 5 passes)
    if (tid < WNODES) sA[tid] = (tid > 0) ? hcnt[tid - 1] : 0u;
    __syncthreads();
    unsigned int* cur = sA;
    unsigned int* nxt = sB;
    for (int off = 1; off < WNODES; off <<= 1) {
        if (tid < WNODES) nxt[tid] = cur[tid] + ((tid >= off) ? cur[tid - off] : 0u);
        __syncthreads();
        unsigned int* t = cur; cur = nxt; nxt = t;
    }
    if (tid < WNODES) hstart[tid] = cur[tid];
    if (tid == WNODES - 1) hstart[WNODES] = cur[WNODES - 1] + hcnt[WNODES - 1];
    __syncthreads();
    if (tid < WNODES) hcnt[tid] = hstart[tid];       // becomes scatter cursor
    __syncthreads();

    // pass 2: scatter into dl-sorted srec (cells L2-hot from pass 1)
    for (unsigned int k = 0; k < c_t; ++k) {
        const unsigned long long rec = seg[1 + k];
        const unsigned int dl = (unsigned int)(rec >> 16) & (WNODES - 1);
        const unsigned int p  = atomicAdd(&hcnt[dl], 1u);
        if (p < CAPW) srec[p] = rec;
    }
    __syncthreads();

    // walk: 16 lanes per node, 8 hids per lane, dual-stream ILP
    const int nl = tid >> 4;            // 0..31
    const int ql = tid & 15;            // hids [8*ql, 8*ql+8)
    unsigned int kb = hstart[nl];
    unsigned int ke = hstart[nl + 1];
    if (kb > CAPW) kb = CAPW;
    if (ke > CAPW) ke = CAPW;

    float4 lo0 = make_float4(0.f, 0.f, 0.f, 0.f), hi0 = lo0;
    float4 lo1 = lo0, hi1 = lo0;
    const uint4* sup4 = (const uint4*)support;       // 16 uint4 per row

    unsigned int k = kb;
    for (; k + 2 <= ke; k += 2) {
        const unsigned long long r0 = srec[k];
        const unsigned long long r1 = srec[k + 1];
        const uint4 u0 = sup4[(size_t)(r0 & 0xFFFFu) * 16 + ql];
        const uint4 u1 = sup4[(size_t)(r1 & 0xFFFFu) * 16 + ql];
        const float w0 = __uint_as_float(((unsigned int)(r0 >> 32)) << 16);
        const float w1 = __uint_as_float(((unsigned int)(r1 >> 32)) << 16);
        const float4 vl0 = bf4(u0.x, u0.y), vh0 = bf4(u0.z, u0.w);
        const float4 vl1 = bf4(u1.x, u1.y), vh1 = bf4(u1.z, u1.w);
        lo0.x = fmaf(w0, vl0.x, lo0.x); lo0.y = fmaf(w0, vl0.y, lo0.y);
        lo0.z = fmaf(w0, vl0.z, lo0.z); lo0.w = fmaf(w0, vl0.w, lo0.w);
        hi0.x = fmaf(w0, vh0.x, hi0.x); hi0.y = fmaf(w0, vh0.y, hi0.y);
        hi0.z = fmaf(w0, vh0.z, hi0.z); hi0.w = fmaf(w0, vh0.w, hi0.w);
        lo1.x = fmaf(w1, vl1.x, lo1.x); lo1.y = fmaf(w1, vl1.y, lo1.y);
        lo1.z = fmaf(w1, vl1.z, lo1.z); lo1.w = fmaf(w1, vl1.w, lo1.w);
        hi1.x = fmaf(w1, vh1.x, hi1.x); hi1.y = fmaf(w1, vh1.y, hi1.y);
        hi1.z = fmaf(w1, vh1.z, hi1.z); hi1.w = fmaf(w1, vh1.w, hi1.w);
    }
    if (k < ke) {
        const unsigned long long r0 = srec[k];
        const uint4 u0 = sup4[(size_t)(r0 & 0xFFFFu) * 16 + ql];
        const float w0 = __uint_as_float(((unsigned int)(r0 >> 32)) << 16);
        const float4 vl0 = bf4(u0.x, u0.y), vh0 = bf4(u0.z, u0.w);
        lo0.x = fmaf(w0, vl0.x, lo0.x); lo0.y = fmaf(w0, vl0.y, lo0.y);
        lo0.z = fmaf(w0, vl0.z, lo0.z); lo0.w = fmaf(w0, vl0.w, lo0.w);
        hi0.x = fmaf(w0, vh0.x, hi0.x); hi0.y = fmaf(w0, vh0.y, hi0.y);
        hi0.z = fmaf(w0, vh0.z, hi0.z); hi0.w = fmaf(w0, vh0.w, hi0.w);
    }

    // epilogue: merge streams + bias + relu + direct store
    const int node = rw * WNODES + nl;               // < 40000 by construction
    {
        float4 lo, hi;
        lo.x = lo0.x + lo1.x; lo.y = lo0.y + lo1.y;
        lo.z = lo0.z + lo1.z; lo.w = lo0.w + lo1.w;
        hi.x = hi0.x + hi1.x; hi.y = hi0.y + hi1.y;
        hi.z = hi0.z + hi1.z; hi.w = hi0.w + hi1.w;
        const float4* b4p = (const float4*)b;
        float4 bl = b4p[ql * 2], bh = b4p[ql * 2 + 1];
        lo.x = fmaxf(lo.x + bl.x, 0.f); lo.y = fmaxf(lo.y + bl.y, 0.f);
        lo.z = fmaxf(lo.z + bl.z, 0.f); lo.w = fmaxf(lo.w + bl.w, 0.f);
        hi.x = fmaxf(hi.x + bh.x, 0.f); hi.y = fmaxf(hi.y + bh.y, 0.f);
        hi.z = fmaxf(hi.z + bh.z, 0.f); hi.w = fmaxf(hi.w + bh.w, 0.f);
        float4* o4 = (float4*)out + (size_t)node * (NHID / 4);
        o4[ql * 2]     = lo;
        o4[ql * 2 + 1] = hi;
    }
}

// ---------------------------------------------------------------------------
// Fallback path (ws too small): fp32 GEMM + atomic scatter
// ---------------------------------------------------------------------------
__global__ __launch_bounds__(256) void gemm_xw(const float* __restrict__ x,
                                               const float* __restrict__ W,
                                               float* __restrict__ support) {
    __shared__ float xs[64 * NFEAT];
    const int tid   = threadIdx.x;
    const int node0 = blockIdx.x * 64;

    const float4* xg  = (const float4*)(x + (size_t)node0 * NFEAT);
    float4*       xs4 = (float4*)xs;
    #pragma unroll
    for (int i = tid; i < 64 * (NFEAT / 4); i += 256) xs4[i] = xg[i];
    __syncthreads();

    const int hg = tid & 31;
    const int ng = tid >> 5;
    const float4* W4 = (const float4*)W;

    float4 acc[8];
    #pragma unroll
    for (int n = 0; n < 8; n++) acc[n] = make_float4(0.f, 0.f, 0.f, 0.f);

    #pragma unroll 4
    for (int k = 0; k < NFEAT; k++) {
        float4 w = W4[k * (NHID / 4) + hg];
        #pragma unroll
        for (int n = 0; n < 8; n++) {
            float xv = xs[(ng * 8 + n) * NFEAT + k];
            acc[n].x = fmaf(xv, w.x, acc[n].x);
            acc[n].y = fmaf(xv, w.y, acc[n].y);
            acc[n].z = fmaf(xv, w.z, acc[n].z);
            acc[n].w = fmaf(xv, w.w, acc[n].w);
        }
    }

    float4* out4 = (float4*)support;
    #pragma unroll
    for (int n = 0; n < 8; n++)
        out4[(size_t)(node0 + ng * 8 + n) * (NHID / 4) + hg] = acc[n];
}

__global__ __launch_bounds__(256) void scatter_edges(const int* __restrict__ ei,
                                                     const float* __restrict__ ew,
                                                     const float* __restrict__ support,
                                                     float* __restrict__ out) {
    const int tid  = threadIdx.x;
    const int lane = tid & 31;
    const int e    = blockIdx.x * 8 + (tid >> 5);
    const int   src = ei[e];
    const int   dst = ei[NEDGES + e];
    const float w   = ew[e];
    const float4* s4 = (const float4*)support;
    float4 v = s4[(size_t)src * (NHID / 4) + lane];
    float* o = out + (size_t)dst * NHID + lane * 4;
    atomicAdd(o + 0, v.x * w);
    atomicAdd(o + 1, v.y * w);
    atomicAdd(o + 2, v.z * w);
    atomicAdd(o + 3, v.w * w);
}

__global__ __launch_bounds__(256) void finalize(float* __restrict__ out,
                                                const float* __restrict__ b) {
    const int i = blockIdx.x * 256 + threadIdx.x;
    float4*       o4 = (float4*)out;
    const float4* b4 = (const float4*)b;
    float4 v  = o4[i];
    float4 bb = b4[i & 31];
    v.x = fmaxf(v.x + bb.x, 0.f);
    v.y = fmaxf(v.y + bb.y, 0.f);
    v.z = fmaxf(v.z + bb.z, 0.f);
    v.w = fmaxf(v.w + bb.w, 0.f);
    o4[i] = v;
}

extern "C" void kernel_launch(void* const* d_in, const int* in_sizes, int n_in,
                              void* d_out, int out_size, void* d_ws, size_t ws_size,
                              hipStream_t stream) {
    const float* x  = (const float*)d_in[0];
    const int*   ei = (const int*)d_in[1];
    const float* ew = (const float*)d_in[2];
    const float* W  = (const float*)d_in[3];
    const float* b  = (const float*)d_in[4];
    float*       out = (float*)d_out;

    char* ws = (char*)d_ws;

    if (ws_size >= WS_NEEDED) {
        unsigned short*     support = (unsigned short*)(ws + SUP_OFF);
        unsigned short*     Wt      = (unsigned short*)(ws + WT_OFF);
        unsigned long long* ebin    = (unsigned long long*)(ws + EBIN_OFF);

        setup_wt<<<128, 256, 0, stream>>>(W, Wt);
        gemm_fill<<<GEMM_BLOCKS + PARTB, 256, 0, stream>>>(
            x, Wt, support, ei, ew, ebin);
        gather_range<<<NW, 512, 0, stream>>>(ebin, support, b, out);
    } else {
        float* support = (float*)(ws + SUP_OFF);
        gemm_xw<<<NNODES / 64, 256, 0, stream>>>(x, W, support);
        hipMemsetAsync(d_out, 0, (size_t)out_size * sizeof(float), stream);
        scatter_edges<<<NEDGES / 8, 256, 0, stream>>>(ei, ew, support, out);
        finalize<<<out_size / 4 / 256, 256, 0, stream>>>(out, b);
    }
}

// Round 15
// 151.763 us; speedup vs baseline: 1.0266x; 1.0266x over previous
//
#include <hip/hip_runtime.h>

#define NNODES 40000
#define NEDGES 640000
#define NFEAT  256
#define NHID   128

// ---- window partition geometry ----
#define WSH    5                        // 32 nodes per window
#define WNODES 32
#define NW     1250                     // 40000/32 exactly
#define PARTB  250                      // fill blocks
#define EPT    10
#define EPB    2560                     // edges per fill block
#define CSLOTS 16                       // cell = 1 header u64 + 15 record slots
#define CAPREC 15                       // records per cell; lambda=2.05, P(>15)~6e-10
#define CAPW   1024                     // gather srec cap; E[cnt]=512
#define GEMM_BLOCKS (NNODES / 64)       // 625

// ---- workspace layout (bytes; ws_size = 256 MiB per R9 poison evidence) ----
#define SUP_OFF  0u                     // support bf16: 10,240,000
#define WT_OFF   10240000u              // Wt bf16: 65,536
#define EBIN_OFF 10305536u              // ebin u64 [NW][PARTB][CSLOTS]: 40,000,000
#define WS_NEEDED (EBIN_OFF + (size_t)NW * PARTB * CSLOTS * 8)   // 50,305,536

typedef float floatx4 __attribute__((ext_vector_type(4)));
typedef __bf16 bf16x8 __attribute__((ext_vector_type(8)));
typedef unsigned short ushort8 __attribute__((ext_vector_type(8)));
union BfFrag { ushort8 s; bf16x8 b; };

__device__ __forceinline__ unsigned short f2bf(float f) {
    unsigned int u = __float_as_uint(f);
    u = (u + 0x7FFFu + ((u >> 16) & 1u)) >> 16;   // RNE
    return (unsigned short)u;
}

// decode 2x(2 bf16) -> float4
__device__ __forceinline__ float4 bf4(unsigned int lo, unsigned int hi) {
    float4 v;
    v.x = __uint_as_float(lo << 16);
    v.y = __uint_as_float(lo & 0xFFFF0000u);
    v.z = __uint_as_float(hi << 16);
    v.w = __uint_as_float(hi & 0xFFFF0000u);
    return v;
}

// ---------------------------------------------------------------------------
// K0: setup — Wt[h][k] = bf16(W[k][h]) only.
// ---------------------------------------------------------------------------
__global__ __launch_bounds__(256) void setup_wt(const float* __restrict__ W,
                                                unsigned short* __restrict__ Wt) {
    const int i = blockIdx.x * 256 + threadIdx.x;
    const int h = i >> 8;
    const int k = i & 255;
    Wt[i] = f2bf(W[k * NHID + h]);
}

// ---------------------------------------------------------------------------
// K1: GEMM (blocks [0,625)) || fill (blocks [625,875)). Unchanged from R14
// (proven): block pb owns cell [rw][pb] (header u64 + 15 slots); LDS u32
// counter gives slot; header written into the block's own private line.
// ---------------------------------------------------------------------------
__global__ __launch_bounds__(256) void gemm_fill(const float* __restrict__ x,
                                                 const unsigned short* __restrict__ Wt,
                                                 unsigned short* __restrict__ support,
                                                 const int* __restrict__ ei,
                                                 const float* __restrict__ ew,
                                                 unsigned long long* __restrict__ ebin) {
    const int tid = threadIdx.x;

    if (blockIdx.x >= GEMM_BLOCKS) {
        // ---- fill path ----
        __shared__ unsigned int ldscur[NW];          // 5000 B
        const int pb   = blockIdx.x - GEMM_BLOCKS;
        const int base = pb * EPB + tid;

        for (int i = tid; i < NW; i += 256) ldscur[i] = 0u;
        __syncthreads();

        int src[EPT], dst[EPT];
        float w[EPT];
        #pragma unroll
        for (int j = 0; j < EPT; j++) {
            const int e = base + j * 256;
            src[j] = ei[e];
            dst[j] = ei[NEDGES + e];
            w[j]   = ew[e];
        }
        #pragma unroll
        for (int j = 0; j < EPT; j++) {
            const int rw = dst[j] >> WSH;
            const unsigned int idx = atomicAdd(&ldscur[rw], 1u);
            if (idx < CAPREC) {
                const unsigned long long rec =
                    ((unsigned long long)f2bf(w[j]) << 32)
                  | ((unsigned long long)(dst[j] & (WNODES - 1)) << 16)
                  | (unsigned long long)(unsigned int)src[j];
                ebin[((size_t)rw * PARTB + pb) * CSLOTS + 1 + idx] = rec;
            }
        }
        __syncthreads();

        for (int i = tid; i < NW; i += 256) {        // strided (R10 lesson)
            unsigned int c = ldscur[i];
            if (c > CAPREC) c = CAPREC;
            ebin[((size_t)i * PARTB + pb) * CSLOTS] = (unsigned long long)c;
        }
        return;
    }

    // ---- GEMM path (unchanged, proven) ----
    const int lane = tid & 63;
    const int wv   = tid >> 6;
    const int m    = lane & 15;
    const int quad = lane >> 4;
    const int node = blockIdx.x * 64 + wv * 16 + m;

    BfFrag afrag[8];
    const float* xrow = x + (size_t)node * NFEAT + quad * 8;
    #pragma unroll
    for (int ks = 0; ks < 8; ks++) {
        float4 f0 = *(const float4*)(xrow + ks * 32);
        float4 f1 = *(const float4*)(xrow + ks * 32 + 4);
        afrag[ks].s[0] = f2bf(f0.x); afrag[ks].s[1] = f2bf(f0.y);
        afrag[ks].s[2] = f2bf(f0.z); afrag[ks].s[3] = f2bf(f0.w);
        afrag[ks].s[4] = f2bf(f1.x); afrag[ks].s[5] = f2bf(f1.y);
        afrag[ks].s[6] = f2bf(f1.z); afrag[ks].s[7] = f2bf(f1.w);
    }

    floatx4 acc[8];
    #pragma unroll
    for (int nt = 0; nt < 8; nt++) acc[nt] = (floatx4){0.f, 0.f, 0.f, 0.f};

    #pragma unroll
    for (int nt = 0; nt < 8; nt++) {
        const unsigned short* wrow = Wt + (size_t)(nt * 16 + m) * NFEAT + quad * 8;
        #pragma unroll
        for (int ks = 0; ks < 8; ks++) {
            BfFrag bfrag;
            bfrag.s = *(const ushort8*)(wrow + ks * 32);
            acc[nt] = __builtin_amdgcn_mfma_f32_16x16x32_bf16(afrag[ks].b, bfrag.b,
                                                              acc[nt], 0, 0, 0);
        }
    }

    const int row0 = blockIdx.x * 64 + wv * 16 + quad * 4;
    #pragma unroll
    for (int nt = 0; nt < 8; nt++) {
        #pragma unroll
        for (int r = 0; r < 4; r++) {
            support[(size_t)(row0 + r) * NHID + nt * 16 + m] = f2bf(acc[nt][r]);
        }
    }
}

// ---------------------------------------------------------------------------
// K2: gather — one block (512 thr) per 32-node window, 1250 blocks.
// R14 lesson: per-thread serial cell reads left half the block idle at 51%
// occupancy / 17% VALU. Now: phase A stages each cell's FIRST LINE
// (header + 7 records, covers P~99.9% at lambda=2.05) into LDS with fully
// coalesced uint4 loads by ALL 512 threads; histogram + scatter are
// slot-parallel all-thread loops over LDS; rare >7-record cells take a
// global overflow path. Walk = R13-proven single-stream. Zero fp atomics.
// ---------------------------------------------------------------------------
__global__ __launch_bounds__(512) void gather_range(
        const unsigned long long* __restrict__ ebin,
        const unsigned short* __restrict__ support,
        const float* __restrict__ b,
        float* __restrict__ out) {
    __shared__ unsigned long long cells[PARTB * 8];  // 16000 B: line0 of each cell
    __shared__ unsigned long long srec[CAPW];        // 8192 B
    __shared__ unsigned int hcnt[WNODES];
    __shared__ unsigned int hstart[WNODES + 1];
    __shared__ unsigned int sA[WNODES], sB[WNODES];

    const int rw  = blockIdx.x;                      // window: nodes [rw*32, rw*32+32)
    const int tid = threadIdx.x;
    const unsigned long long* gbase = ebin + (size_t)rw * PARTB * CSLOTS;

    // phase A: coalesced stage of cell first-lines (header + records 0..6)
    {
        const uint4* g4 = (const uint4*)gbase;       // cell c line0 = g4[c*8 + 0..3]
        uint4*       l4 = (uint4*)cells;             // LDS [c*4 + 0..3]
        for (int i = tid; i < PARTB * 4; i += 512) {
            const int c = i >> 2, p = i & 3;
            l4[i] = g4[c * 8 + p];
        }
    }
    if (tid < WNODES) hcnt[tid] = 0u;
    __syncthreads();

    // phase B: histogram dl — slot-parallel over LDS (all threads)
    for (int i = tid; i < PARTB * 7; i += 512) {
        const int c = i / 7, s = i - c * 7;
        unsigned int ct = (unsigned int)cells[c * 8];
        if (ct > CAPREC) ct = CAPREC;
        const unsigned int c7 = ct < 7u ? ct : 7u;
        if ((unsigned int)s < c7)
            atomicAdd(&hcnt[(unsigned int)(cells[c * 8 + 1 + s] >> 16) & (WNODES - 1)], 1u);
    }
    for (int c = tid; c < PARTB; c += 512) {         // overflow: records 7..ct-1
        unsigned int ct = (unsigned int)cells[c * 8];
        if (ct > CAPREC) ct = CAPREC;
        for (unsigned int k = 7; k < ct; ++k)
            atomicAdd(&hcnt[(unsigned int)(gbase[(size_t)c * CSLOTS + 1 + k] >> 16) & (WNODES - 1)], 1u);
    }
    __syncthreads();

    // exclusive scan over 32 (Hillis-Steele, 5 passes)
    if (tid < WNODES) sA[tid] = (tid > 0) ? hcnt[tid - 1] : 0u;
    __syncthreads();
    unsigned int* cur = sA;
    unsigned int* nxt = sB;
    for (int off = 1; off < WNODES; off <<= 1) {
        if (tid < WNODES) nxt[tid] = cur[tid] + ((tid >= off) ? cur[tid - off] : 0u);
        __syncthreads();
        unsigned int* t = cur; cur = nxt; nxt = t;
    }
    if (tid < WNODES) hstart[tid] = cur[tid];
    if (tid == WNODES - 1) hstart[WNODES] = cur[WNODES - 1] + hcnt[WNODES - 1];
    __syncthreads();
    if (tid < WNODES) hcnt[tid] = hstart[tid];       // becomes scatter cursor
    __syncthreads();

    // phase C: scatter into dl-sorted srec — slot-parallel over LDS
    for (int i = tid; i < PARTB * 7; i += 512) {
        const int c = i / 7, s = i - c * 7;
        unsigned int ct = (unsigned int)cells[c * 8];
        if (ct > CAPREC) ct = CAPREC;
        const unsigned int c7 = ct < 7u ? ct : 7u;
        if ((unsigned int)s < c7) {
            const unsigned long long rec = cells[c * 8 + 1 + s];
            const unsigned int dl = (unsigned int)(rec >> 16) & (WNODES - 1);
            const unsigned int p  = atomicAdd(&hcnt[dl], 1u);
            if (p < CAPW) srec[p] = rec;
        }
    }
    for (int c = tid; c < PARTB; c += 512) {         // overflow: records 7..ct-1
        unsigned int ct = (unsigned int)cells[c * 8];
        if (ct > CAPREC) ct = CAPREC;
        for (unsigned int k = 7; k < ct; ++k) {
            const unsigned long long rec = gbase[(size_t)c * CSLOTS + 1 + k];
            const unsigned int dl = (unsigned int)(rec >> 16) & (WNODES - 1);
            const unsigned int p  = atomicAdd(&hcnt[dl], 1u);
            if (p < CAPW) srec[p] = rec;
        }
    }
    __syncthreads();

    // walk: 16 lanes per node, 8 hids per lane, 1 uint4 per record (R13-proven)
    const int nl = tid >> 4;            // 0..31
    const int ql = tid & 15;            // hids [8*ql, 8*ql+8)
    unsigned int kb = hstart[nl];
    unsigned int ke = hstart[nl + 1];
    if (kb > CAPW) kb = CAPW;
    if (ke > CAPW) ke = CAPW;

    float4 lo = make_float4(0.f, 0.f, 0.f, 0.f);
    float4 hi = lo;
    const uint4* sup4 = (const uint4*)support;       // 16 uint4 per row

    #pragma unroll 2
    for (unsigned int k = kb; k < ke; ++k) {
        const unsigned long long rec = srec[k];      // broadcast in 16-lane group
        const float w  = __uint_as_float(((unsigned int)(rec >> 32)) << 16);
        const int   sc = (int)(rec & 0xFFFFu);
        const uint4 u  = sup4[(size_t)sc * 16 + ql];
        const float4 vl = bf4(u.x, u.y), vh = bf4(u.z, u.w);
        lo.x = fmaf(w, vl.x, lo.x); lo.y = fmaf(w, vl.y, lo.y);
        lo.z = fmaf(w, vl.z, lo.z); lo.w = fmaf(w, vl.w, lo.w);
        hi.x = fmaf(w, vh.x, hi.x); hi.y = fmaf(w, vh.y, hi.y);
        hi.z = fmaf(w, vh.z, hi.z); hi.w = fmaf(w, vh.w, hi.w);
    }

    // epilogue: bias + relu + direct store (lane owns hids exclusively)
    const int node = rw * WNODES + nl;               // < 40000 by construction
    {
        const float4* b4p = (const float4*)b;
        float4 bl = b4p[ql * 2], bh = b4p[ql * 2 + 1];
        lo.x = fmaxf(lo.x + bl.x, 0.f); lo.y = fmaxf(lo.y + bl.y, 0.f);
        lo.z = fmaxf(lo.z + bl.z, 0.f); lo.w = fmaxf(lo.w + bl.w, 0.f);
        hi.x = fmaxf(hi.x + bh.x, 0.f); hi.y = fmaxf(hi.y + bh.y, 0.f);
        hi.z = fmaxf(hi.z + bh.z, 0.f); hi.w = fmaxf(hi.w + bh.w, 0.f);
        float4* o4 = (float4*)out + (size_t)node * (NHID / 4);
        o4[ql * 2]     = lo;
        o4[ql * 2 + 1] = hi;
    }
}

// ---------------------------------------------------------------------------
// Fallback path (ws too small): fp32 GEMM + atomic scatter
// ---------------------------------------------------------------------------
__global__ __launch_bounds__(256) void gemm_xw(const float* __restrict__ x,
                                               const float* __restrict__ W,
                                               float* __restrict__ support) {
    __shared__ float xs[64 * NFEAT];
    const int tid   = threadIdx.x;
    const int node0 = blockIdx.x * 64;

    const float4* xg  = (const float4*)(x + (size_t)node0 * NFEAT);
    float4*       xs4 = (float4*)xs;
    #pragma unroll
    for (int i = tid; i < 64 * (NFEAT / 4); i += 256) xs4[i] = xg[i];
    __syncthreads();

    const int hg = tid & 31;
    const int ng = tid >> 5;
    const float4* W4 = (const float4*)W;

    float4 acc[8];
    #pragma unroll
    for (int n = 0; n < 8; n++) acc[n] = make_float4(0.f, 0.f, 0.f, 0.f);

    #pragma unroll 4
    for (int k = 0; k < NFEAT; k++) {
        float4 w = W4[k * (NHID / 4) + hg];
        #pragma unroll
        for (int n = 0; n < 8; n++) {
            float xv = xs[(ng * 8 + n) * NFEAT + k];
            acc[n].x = fmaf(xv, w.x, acc[n].x);
            acc[n].y = fmaf(xv, w.y, acc[n].y);
            acc[n].z = fmaf(xv, w.z, acc[n].z);
            acc[n].w = fmaf(xv, w.w, acc[n].w);
        }
    }

    float4* out4 = (float4*)support;
    #pragma unroll
    for (int n = 0; n < 8; n++)
        out4[(size_t)(node0 + ng * 8 + n) * (NHID / 4) + hg] = acc[n];
}

__global__ __launch_bounds__(256) void scatter_edges(const int* __restrict__ ei,
                                                     const float* __restrict__ ew,
                                                     const float* __restrict__ support,
                                                     float* __restrict__ out) {
    const int tid  = threadIdx.x;
    const int lane = tid & 31;
    const int e    = blockIdx.x * 8 + (tid >> 5);
    const int   src = ei[e];
    const int   dst = ei[NEDGES + e];
    const float w   = ew[e];
    const float4* s4 = (const float4*)support;
    float4 v = s4[(size_t)src * (NHID / 4) + lane];
    float* o = out + (size_t)dst * NHID + lane * 4;
    atomicAdd(o + 0, v.x * w);
    atomicAdd(o + 1, v.y * w);
    atomicAdd(o + 2, v.z * w);
    atomicAdd(o + 3, v.w * w);
}

__global__ __launch_bounds__(256) void finalize(float* __restrict__ out,
                                                const float* __restrict__ b) {
    const int i = blockIdx.x * 256 + threadIdx.x;
    float4*       o4 = (float4*)out;
    const float4* b4 = (const float4*)b;
    float4 v  = o4[i];
    float4 bb = b4[i & 31];
    v.x = fmaxf(v.x + bb.x, 0.f);
    v.y = fmaxf(v.y + bb.y, 0.f);
    v.z = fmaxf(v.z + bb.z, 0.f);
    v.w = fmaxf(v.w + bb.w, 0.f);
    o4[i] = v;
}

extern "C" void kernel_launch(void* const* d_in, const int* in_sizes, int n_in,
                              void* d_out, int out_size, void* d_ws, size_t ws_size,
                              hipStream_t stream) {
    const float* x  = (const float*)d_in[0];
    const int*   ei = (const int*)d_in[1];
    const float* ew = (const float*)d_in[2];
    const float* W  = (const float*)d_in[3];
    const float* b  = (const float*)d_in[4];
    float*       out = (float*)d_out;

    char* ws = (char*)d_ws;

    if (ws_size >= WS_NEEDED) {
        unsigned short*     support = (unsigned short*)(ws + SUP_OFF);
        unsigned short*     Wt      = (unsigned short*)(ws + WT_OFF);
        unsigned long long* ebin    = (unsigned long long*)(ws + EBIN_OFF);

        setup_wt<<<128, 256, 0, stream>>>(W, Wt);
        gemm_fill<<<GEMM_BLOCKS + PARTB, 256, 0, stream>>>(
            x, Wt, support, ei, ew, ebin);
        gather_range<<<NW, 512, 0, stream>>>(ebin, support, b, out);
    } else {
        float* support = (float*)(ws + SUP_OFF);
        gemm_xw<<<NNODES / 64, 256, 0, stream>>>(x, W, support);
        hipMemsetAsync(d_out, 0, (size_t)out_size * sizeof(float), stream);
        scatter_edges<<<NEDGES / 8, 256, 0, stream>>>(ei, ew, support, out);
        finalize<<<out_size / 4 / 256, 256, 0, stream>>>(out, b);
    }
}